// Round 2
// baseline (782.831 us; speedup 1.0000x reference)
//
#include <hip/hip_runtime.h>
#include <math.h>

// ---------------- constants ----------------
#define BDIM   4096
#define IN_DIM 1024
#define HID    512
#define LAT    2048       // 16 tokens * 128
#define EMB    128
#define NCODE  1024
#define NROWS  65536      // B * NUM_TOKENS
#define OUT_REC  (4096 * 1024)
#define OUT_IDX  (OUT_REC)          // offset of indices region
#define OUT_LOSS (OUT_REC + 65536)

#define BM 64
#define BN 64
#define BK 16

__device__ __forceinline__ float gelu_exact(float x) {
    return 0.5f * x * (1.0f + erff(x * 0.7071067811865476f));
}

// C[M,N] = act(A[M,K] @ W[K,N] + bias), all row-major, M%64==0, N%64==0, K%16==0
template<bool GELU>
__global__ __launch_bounds__(256) void gemm_bias_kernel(
    const float* __restrict__ A, const float* __restrict__ W,
    const float* __restrict__ bias, float* __restrict__ C,
    int M, int N, int K)
{
    __shared__ float As[BK][BM + 4];   // [k][m], pad 4 -> 2-way max on write, clean b128 reads
    __shared__ float Ws[BK][BN];       // [k][n]

    const int tid = threadIdx.x;
    const int tx = tid & 15, ty = tid >> 4;
    const int bm = blockIdx.x * BM;
    const int bn = blockIdx.y * BN;

    // staging maps
    const int a_row = tid >> 2;          // 0..63
    const int a_k   = (tid & 3) * 4;     // 0,4,8,12
    const int w_k   = tid >> 4;          // 0..15
    const int w_n   = (tid & 15) * 4;    // 0..60

    const float* Ab = A + (size_t)bm * K;
    const float* Wb = W + bn;

    float acc[4][4] = {};

    for (int k0 = 0; k0 < K; k0 += BK) {
        float4 av = *reinterpret_cast<const float4*>(Ab + (size_t)a_row * K + k0 + a_k);
        float4 wv = *reinterpret_cast<const float4*>(Wb + (size_t)(k0 + w_k) * N + w_n);
        __syncthreads();   // previous iteration's reads done
        As[a_k + 0][a_row] = av.x;
        As[a_k + 1][a_row] = av.y;
        As[a_k + 2][a_row] = av.z;
        As[a_k + 3][a_row] = av.w;
        *reinterpret_cast<float4*>(&Ws[w_k][w_n]) = wv;
        __syncthreads();
        #pragma unroll
        for (int kk = 0; kk < BK; ++kk) {
            float4 a4 = *reinterpret_cast<const float4*>(&As[kk][ty * 4]);
            float4 w4 = *reinterpret_cast<const float4*>(&Ws[kk][tx * 4]);
            float a_[4] = {a4.x, a4.y, a4.z, a4.w};
            float w_[4] = {w4.x, w4.y, w4.z, w4.w};
            #pragma unroll
            for (int i = 0; i < 4; ++i)
                #pragma unroll
                for (int j = 0; j < 4; ++j)
                    acc[i][j] = fmaf(a_[i], w_[j], acc[i][j]);
        }
    }

    #pragma unroll
    for (int i = 0; i < 4; ++i) {
        const int row = bm + ty * 4 + i;
        #pragma unroll
        for (int j = 0; j < 4; ++j) {
            const int col = bn + tx * 4 + j;
            float v = acc[i][j] + bias[col];
            if (GELU) v = gelu_exact(v);
            C[(size_t)row * N + col] = v;
        }
    }
}

// per-code squared norm
__global__ __launch_bounds__(128) void cnorm_kernel(const float* __restrict__ cb,
                                                    float* __restrict__ cnorm) {
    const int c = blockIdx.x;
    float v = cb[(size_t)c * EMB + threadIdx.x];
    float s = v * v;
    #pragma unroll
    for (int off = 32; off > 0; off >>= 1) s += __shfl_down(s, off, 64);
    __shared__ float ps[2];
    if ((threadIdx.x & 63) == 0) ps[threadIdx.x >> 6] = s;
    __syncthreads();
    if (threadIdx.x == 0) cnorm[c] = ps[0] + ps[1];
}

// Fused VQ: per block 64 z-rows. dist = cnorm - 2*z.c, argmin (first-min), gather q
// in place over Z, commit-loss partial via atomic.
__global__ __launch_bounds__(256) void vq_kernel(
    float* __restrict__ Z,               // [65536][128], overwritten with q
    const float* __restrict__ cb,        // [1024][128]
    const float* __restrict__ cnorm,     // [1024]
    float* __restrict__ idx_out,         // [65536] float indices
    float* __restrict__ loss_accum)
{
    __shared__ float Zs[EMB][BM + 4];    // z^T tile [k][row]
    __shared__ float Cs[EMB][BM + 4];    // code^T chunk [k][code]
    __shared__ float red_d[64][17];
    __shared__ int   red_i[64][17];
    __shared__ int   bidx_s[64];
    __shared__ float lred[4];

    const int tid = threadIdx.x;
    const int tx = tid & 15, ty = tid >> 4;
    const int r0 = blockIdx.x * 64;

    const int s_row = tid >> 2;          // 0..63
    const int s_kq  = (tid & 3) * 4;     // 0,4,8,12

    // stage z tile (transposed)
    #pragma unroll
    for (int kt = 0; kt < 8; ++kt) {
        const int k = kt * 16 + s_kq;
        float4 v = *reinterpret_cast<const float4*>(&Z[(size_t)(r0 + s_row) * EMB + k]);
        Zs[k + 0][s_row] = v.x; Zs[k + 1][s_row] = v.y;
        Zs[k + 2][s_row] = v.z; Zs[k + 3][s_row] = v.w;
    }

    float best[4]; int bidx[4];
    #pragma unroll
    for (int i = 0; i < 4; ++i) { best[i] = 3.4e38f; bidx[i] = 0; }

    for (int cc = 0; cc < 16; ++cc) {
        __syncthreads();   // Zs ready (iter 0) / prior Cs reads done
        const int c0 = cc * 64;
        #pragma unroll
        for (int kt = 0; kt < 8; ++kt) {
            const int k = kt * 16 + s_kq;
            float4 v = *reinterpret_cast<const float4*>(&cb[(size_t)(c0 + s_row) * EMB + k]);
            Cs[k + 0][s_row] = v.x; Cs[k + 1][s_row] = v.y;
            Cs[k + 2][s_row] = v.z; Cs[k + 3][s_row] = v.w;
        }
        __syncthreads();

        float acc[4][4] = {};
        #pragma unroll 16
        for (int kk = 0; kk < EMB; ++kk) {
            float4 a4 = *reinterpret_cast<const float4*>(&Zs[kk][ty * 4]);
            float4 c4 = *reinterpret_cast<const float4*>(&Cs[kk][tx * 4]);
            float a_[4] = {a4.x, a4.y, a4.z, a4.w};
            float c_[4] = {c4.x, c4.y, c4.z, c4.w};
            #pragma unroll
            for (int i = 0; i < 4; ++i)
                #pragma unroll
                for (int j = 0; j < 4; ++j)
                    acc[i][j] = fmaf(a_[i], c_[j], acc[i][j]);
        }
        // argmin update (codes ascend within thread -> strict < keeps first min)
        #pragma unroll
        for (int j = 0; j < 4; ++j) {
            const int c = c0 + tx * 4 + j;
            const float cn = cnorm[c];
            #pragma unroll
            for (int i = 0; i < 4; ++i) {
                const float d = cn - 2.0f * acc[i][j];
                if (d < best[i]) { best[i] = d; bidx[i] = c; }
            }
        }
    }

    #pragma unroll
    for (int i = 0; i < 4; ++i) {
        red_d[ty * 4 + i][tx] = best[i];
        red_i[ty * 4 + i][tx] = bidx[i];
    }
    __syncthreads();
    if (tid < 64) {
        float bd = red_d[tid][0]; int bi = red_i[tid][0];
        #pragma unroll
        for (int t = 1; t < 16; ++t) {
            const float d = red_d[tid][t]; const int ii = red_i[tid][t];
            if (d < bd || (d == bd && ii < bi)) { bd = d; bi = ii; }
        }
        idx_out[r0 + tid] = (float)bi;
        bidx_s[tid] = bi;
    }
    __syncthreads();

    // gather q over Z in place + commit loss
    float lsum = 0.0f;
    #pragma unroll
    for (int p = 0; p < 32; ++p) {
        const int el = tid + p * 256;
        const int row = el >> 7, k = el & 127;
        const float qv = cb[(size_t)bidx_s[row] * EMB + k];
        const float zv = Zs[k][row];
        const float dv = qv - zv;
        lsum += dv * dv;
        Z[(size_t)(r0 + row) * EMB + k] = qv;
    }
    #pragma unroll
    for (int off = 32; off > 0; off >>= 1) lsum += __shfl_down(lsum, off, 64);
    if ((tid & 63) == 0) lred[tid >> 6] = lsum;
    __syncthreads();
    if (tid == 0) atomicAdd(loss_accum, lred[0] + lred[1] + lred[2] + lred[3]);
}

__global__ void loss_fin_kernel(const float* __restrict__ acc, float* __restrict__ out) {
    out[0] = acc[0] * (1.0f / 8388608.0f);   // mean over 65536*128
}

extern "C" void kernel_launch(void* const* d_in, const int* in_sizes, int n_in,
                              void* d_out, int out_size, void* d_ws, size_t ws_size,
                              hipStream_t stream) {
    const float* x   = (const float*)d_in[0];
    const float* eW1 = (const float*)d_in[1];
    const float* eb1 = (const float*)d_in[2];
    const float* eW2 = (const float*)d_in[3];
    const float* eb2 = (const float*)d_in[4];
    const float* eW3 = (const float*)d_in[5];
    const float* eb3 = (const float*)d_in[6];
    const float* dW1 = (const float*)d_in[7];
    const float* db1 = (const float*)d_in[8];
    const float* dW2 = (const float*)d_in[9];
    const float* db2 = (const float*)d_in[10];
    const float* dW3 = (const float*)d_in[11];
    const float* db3 = (const float*)d_in[12];
    const float* cb  = (const float*)d_in[13];

    float* out = (float*)d_out;
    float* ws  = (float*)d_ws;

    float* h1    = ws;                       // 4096*512
    float* h2    = h1 + (size_t)BDIM * HID;  // 4096*512
    float* z     = h2 + (size_t)BDIM * HID;  // 4096*2048 (becomes q in place)
    float* cnorm = z + (size_t)BDIM * LAT;   // 1024
    float* lacc  = cnorm + NCODE;            // 1

    hipMemsetAsync(lacc, 0, sizeof(float), stream);
    cnorm_kernel<<<NCODE, 128, 0, stream>>>(cb, cnorm);

    // encoder
    gemm_bias_kernel<true ><<<dim3(BDIM / BM, HID / BN), 256, 0, stream>>>(x,  eW1, eb1, h1, BDIM, HID, IN_DIM);
    gemm_bias_kernel<true ><<<dim3(BDIM / BM, HID / BN), 256, 0, stream>>>(h1, eW2, eb2, h2, BDIM, HID, HID);
    gemm_bias_kernel<false><<<dim3(BDIM / BM, LAT / BN), 256, 0, stream>>>(h2, eW3, eb3, z,  BDIM, LAT, HID);

    // VQ (writes q into z, indices as float, loss partials)
    vq_kernel<<<NROWS / 64, 256, 0, stream>>>(z, cb, cnorm, out + OUT_IDX, lacc);

    // decoder (input q == z buffer)
    gemm_bias_kernel<true ><<<dim3(BDIM / BM, HID / BN),    256, 0, stream>>>(z,  dW1, db1, h1, BDIM, HID, LAT);
    gemm_bias_kernel<true ><<<dim3(BDIM / BM, HID / BN),    256, 0, stream>>>(h1, dW2, db2, h2, BDIM, HID, HID);
    gemm_bias_kernel<false><<<dim3(BDIM / BM, IN_DIM / BN), 256, 0, stream>>>(h2, dW3, db3, out, BDIM, IN_DIM, HID);

    loss_fin_kernel<<<1, 1, 0, stream>>>(lacc, out + OUT_LOSS);
}

// Round 3
// 772.582 us; speedup vs baseline: 1.0133x; 1.0133x over previous
//
#include <hip/hip_runtime.h>
#include <hip/hip_bf16.h>
#include <math.h>

// ---------------- constants ----------------
#define BDIM   4096
#define IN_DIM 1024
#define HID    512
#define LAT    2048
#define EMB    128
#define NCODE  1024
#define NROWS  65536
#define OUT_REC  (4096 * 1024)
#define OUT_IDX  (OUT_REC)
#define OUT_LOSS (OUT_REC + 65536)

// ws layout (float offsets)
#define H1_OFF    0u                       // 2M floats: enc h1, then h1hi/h1lo bf16
#define H2_OFF    (2u*1024*1024)           // 2M floats: enc h2, then h2hi/h2lo bf16
#define Z_OFF     (4u*1024*1024)           // 8M floats: z fp32, overwritten by qpack (hi|lo per token row)
#define CBT_OFF   (12u*1024*1024)          // 131072 floats: cbT [128][1024]
#define CNORM_OFF (CBT_OFF + 131072u)      // 1024
#define LACC_OFF  (CNORM_OFF + 1024u)      // 1 (+pad)
#define WT_OFF    (LACC_OFF + 8u)          // weight splits (ushort region)

typedef __attribute__((ext_vector_type(8))) __bf16 bf16x8;
typedef __attribute__((ext_vector_type(4))) float f32x4;
typedef __attribute__((ext_vector_type(8))) unsigned short u16x8;

__device__ __forceinline__ float gelu_exact(float x) {
    return 0.5f * x * (1.0f + erff(x * 0.7071067811865476f));
}

__device__ __forceinline__ void split_bf16(float v, unsigned short& hi, unsigned short& lo) {
    __hip_bfloat16 h = __float2bfloat16(v);
    float hf = __bfloat162float(h);
    __hip_bfloat16 l = __float2bfloat16(v - hf);
    hi = *reinterpret_cast<unsigned short*>(&h);
    lo = *reinterpret_cast<unsigned short*>(&l);
}

// ---------- fp32 GEMM (encoder path — precision-critical, unchanged) ----------
template<bool GELU>
__global__ __launch_bounds__(256) void gemm_bias_kernel(
    const float* __restrict__ A, const float* __restrict__ W,
    const float* __restrict__ bias, float* __restrict__ C,
    int M, int N, int K)
{
    __shared__ float As[16][64 + 4];
    __shared__ float Ws[16][64];
    const int tid = threadIdx.x;
    const int tx = tid & 15, ty = tid >> 4;
    const int bm = blockIdx.x * 64;
    const int bn = blockIdx.y * 64;
    const int a_row = tid >> 2, a_k = (tid & 3) * 4;
    const int w_k = tid >> 4, w_n = (tid & 15) * 4;
    const float* Ab = A + (size_t)bm * K;
    const float* Wb = W + bn;
    float acc[4][4] = {};
    for (int k0 = 0; k0 < K; k0 += 16) {
        float4 av = *reinterpret_cast<const float4*>(Ab + (size_t)a_row * K + k0 + a_k);
        float4 wv = *reinterpret_cast<const float4*>(Wb + (size_t)(k0 + w_k) * N + w_n);
        __syncthreads();
        As[a_k + 0][a_row] = av.x; As[a_k + 1][a_row] = av.y;
        As[a_k + 2][a_row] = av.z; As[a_k + 3][a_row] = av.w;
        *reinterpret_cast<float4*>(&Ws[w_k][w_n]) = wv;
        __syncthreads();
        #pragma unroll
        for (int kk = 0; kk < 16; ++kk) {
            float4 a4 = *reinterpret_cast<const float4*>(&As[kk][ty * 4]);
            float4 w4 = *reinterpret_cast<const float4*>(&Ws[kk][tx * 4]);
            float a_[4] = {a4.x, a4.y, a4.z, a4.w};
            float w_[4] = {w4.x, w4.y, w4.z, w4.w};
            #pragma unroll
            for (int i = 0; i < 4; ++i)
                #pragma unroll
                for (int j = 0; j < 4; ++j)
                    acc[i][j] = fmaf(a_[i], w_[j], acc[i][j]);
        }
    }
    #pragma unroll
    for (int i = 0; i < 4; ++i) {
        const int row = bm + ty * 4 + i;
        #pragma unroll
        for (int j = 0; j < 4; ++j) {
            const int col = bn + tx * 4 + j;
            float v = acc[i][j] + bias[col];
            if (GELU) v = gelu_exact(v);
            C[(size_t)row * N + col] = v;
        }
    }
}

// ---------- prep: codebook norm ----------
__global__ __launch_bounds__(128) void cnorm_kernel(const float* __restrict__ cb,
                                                    float* __restrict__ cnorm) {
    const int c = blockIdx.x;
    float v = cb[(size_t)c * EMB + threadIdx.x];
    float s = v * v;
    #pragma unroll
    for (int off = 32; off > 0; off >>= 1) s += __shfl_down(s, off, 64);
    __shared__ float ps[2];
    if ((threadIdx.x & 63) == 0) ps[threadIdx.x >> 6] = s;
    __syncthreads();
    if (threadIdx.x == 0) cnorm[c] = ps[0] + ps[1];
}

// ---------- prep: fp32 transpose (cb -> cbT) ----------
__global__ __launch_bounds__(256) void transpose_f32_kernel(const float* __restrict__ in,
        float* __restrict__ out, int R, int C) {   // out[C][R]
    __shared__ float tile[32][33];
    const int r0 = blockIdx.y * 32, c0 = blockIdx.x * 32;
    const int tx = threadIdx.x, ty = threadIdx.y;  // (32,8)
    #pragma unroll
    for (int i = 0; i < 4; ++i)
        tile[ty * 4 + i][tx] = in[(size_t)(r0 + ty * 4 + i) * C + c0 + tx];
    __syncthreads();
    #pragma unroll
    for (int i = 0; i < 4; ++i)
        out[(size_t)(c0 + ty * 4 + i) * R + r0 + tx] = tile[tx][ty * 4 + i];
}

// ---------- prep: split+transpose weights W[K][N] -> hiT/loT [N][K] bf16 ----------
__global__ __launch_bounds__(256) void wsplitT_kernel(const float* __restrict__ W,
        unsigned short* __restrict__ hiT, unsigned short* __restrict__ loT, int K, int N) {
    __shared__ float tile[32][33];
    const int k0 = blockIdx.y * 32, n0 = blockIdx.x * 32;
    const int tx = threadIdx.x, ty = threadIdx.y;  // (32,8)
    #pragma unroll
    for (int i = 0; i < 4; ++i)
        tile[ty * 4 + i][tx] = W[(size_t)(k0 + ty * 4 + i) * N + n0 + tx];
    __syncthreads();
    #pragma unroll
    for (int i = 0; i < 4; ++i) {
        float v = tile[tx][ty * 4 + i];
        unsigned short h, l; split_bf16(v, h, l);
        size_t o = (size_t)(n0 + ty * 4 + i) * K + k0 + tx;
        hiT[o] = h; loT[o] = l;
    }
}

// ---------- VQ v2: 64 rows/block, 256-code chunks, 8x8 per thread ----------
__global__ __launch_bounds__(256) void vq2_kernel(
    const float* __restrict__ Z, unsigned short* __restrict__ qpack,
    const float* __restrict__ cbT, const float* __restrict__ cb,
    const float* __restrict__ cnorm,
    float* __restrict__ idx_out, float* __restrict__ loss_accum)
{
    __shared__ float Zs[128][68];      // [k][row]
    __shared__ float Cs[32][260];      // [k][code-chunk]
    __shared__ int bidx_s[64];
    __shared__ float lred[4];
    const int tid = threadIdx.x;
    const int tx = tid & 31, ty = tid >> 5;      // tx: 8 codes, ty: 8 rows
    const int r0 = blockIdx.x * 64;

    #pragma unroll
    for (int p = 0; p < 8; ++p) {                // stage Zs transposed, once
        int s = tid + p * 256;
        int row = s >> 5, k4 = (s & 31) * 4;
        float4 v = *reinterpret_cast<const float4*>(&Z[(size_t)(r0 + row) * EMB + k4]);
        Zs[k4 + 0][row] = v.x; Zs[k4 + 1][row] = v.y;
        Zs[k4 + 2][row] = v.z; Zs[k4 + 3][row] = v.w;
    }

    float best[8]; int bidx[8];
    #pragma unroll
    for (int i = 0; i < 8; ++i) { best[i] = 3.4e38f; bidx[i] = 0; }

    for (int cc = 0; cc < 4; ++cc) {
        float acc[8][8] = {};
        for (int kc = 0; kc < 4; ++kc) {
            __syncthreads();
            #pragma unroll
            for (int p = 0; p < 8; ++p) {        // stage Cs[32][256] from cbT
                int s = tid + p * 256;
                int kr = s >> 6, c4 = (s & 63) * 4;
                float4 v = *reinterpret_cast<const float4*>(
                    &cbT[(size_t)(kc * 32 + kr) * NCODE + cc * 256 + c4]);
                *reinterpret_cast<float4*>(&Cs[kr][c4]) = v;
            }
            __syncthreads();
            #pragma unroll
            for (int kk = 0; kk < 32; ++kk) {
                f32x4 a0 = *reinterpret_cast<const f32x4*>(&Zs[kc * 32 + kk][ty * 8]);
                f32x4 a1 = *reinterpret_cast<const f32x4*>(&Zs[kc * 32 + kk][ty * 8 + 4]);
                f32x4 c0 = *reinterpret_cast<const f32x4*>(&Cs[kk][tx * 8]);
                f32x4 c1 = *reinterpret_cast<const f32x4*>(&Cs[kk][tx * 8 + 4]);
                float a[8] = {a0.x, a0.y, a0.z, a0.w, a1.x, a1.y, a1.z, a1.w};
                float c[8] = {c0.x, c0.y, c0.z, c0.w, c1.x, c1.y, c1.z, c1.w};
                #pragma unroll
                for (int i = 0; i < 8; ++i)
                    #pragma unroll
                    for (int j = 0; j < 8; ++j)
                        acc[i][j] = fmaf(a[i], c[j], acc[i][j]);
            }
        }
        #pragma unroll
        for (int j = 0; j < 8; ++j) {            // codes ascend with cc,j -> strict < = first-min
            int c = cc * 256 + tx * 8 + j;
            float cn = cnorm[c];
            #pragma unroll
            for (int i = 0; i < 8; ++i) {
                float d = cn - 2.0f * acc[i][j];
                if (d < best[i]) { best[i] = d; bidx[i] = c; }
            }
        }
    }
    // reduce across tx (32-lane halves), tie-break smaller index
    #pragma unroll
    for (int i = 0; i < 8; ++i) {
        float bd = best[i]; int bi = bidx[i];
        #pragma unroll
        for (int m = 1; m < 32; m <<= 1) {
            float od = __shfl_xor(bd, m); int oi = __shfl_xor(bi, m);
            if (od < bd || (od == bd && oi < bi)) { bd = od; bi = oi; }
        }
        if (tx == 0) {
            int row = ty * 8 + i;
            idx_out[r0 + row] = (float)bi;
            bidx_s[row] = bi;
        }
    }
    __syncthreads();
    // gather q -> qpack (in-place over the z rows this block read), commit loss
    float lsum = 0.0f;
    #pragma unroll
    for (int p = 0; p < 32; ++p) {
        int el = p * 256 + tid;
        int row = el >> 7, k = el & 127;
        int bi = bidx_s[row];
        float qv = cb[(size_t)bi * EMB + k];
        float zv = Zs[k][row];
        float dv = qv - zv;
        lsum += dv * dv;
        unsigned short h, l; split_bf16(qv, h, l);
        size_t base = (size_t)(r0 + row) * 256;
        qpack[base + k] = h;
        qpack[base + 128 + k] = l;
    }
    #pragma unroll
    for (int off = 32; off > 0; off >>= 1) lsum += __shfl_down(lsum, off, 64);
    if ((tid & 63) == 0) lred[tid >> 6] = lsum;
    __syncthreads();
    if (tid == 0) atomicAdd(loss_accum, lred[0] + lred[1] + lred[2] + lred[3]);
}

// ---------- decoder: split-bf16 3-product MFMA GEMM, 128x128 tile, BK=32 ----------
// AMODE 0: A as separate hi/lo [M][K]; 1: A = qpack (per-token [128 hi|128 lo])
// OMODE 0: fp32 C out; 1: split hi/lo bf16 out
template<int AMODE, bool GELU, int OMODE>
__global__ __launch_bounds__(256) void mfma_gemm_kernel(
    const unsigned short* __restrict__ Ahi, const unsigned short* __restrict__ Alo,
    const unsigned short* __restrict__ BThi, const unsigned short* __restrict__ BTlo,
    const float* __restrict__ bias,
    float* __restrict__ Cf, unsigned short* __restrict__ Ohi, unsigned short* __restrict__ Olo,
    int M, int N, int K)
{
    __shared__ unsigned short AsH[128][40], AsL[128][40], BsH[128][40], BsL[128][40];
    const int tid = threadIdx.x;
    const int lane = tid & 63, wid = tid >> 6;
    const int wm = (wid >> 1) * 64, wn = (wid & 1) * 64;
    const int m0 = blockIdx.x * 128, n0 = blockIdx.y * 128;

    f32x4 acc[4][4];
    #pragma unroll
    for (int i = 0; i < 4; ++i)
        #pragma unroll
        for (int j = 0; j < 4; ++j)
            acc[i][j] = f32x4{0.f, 0.f, 0.f, 0.f};

    const int ar0 = tid >> 1;                  // staging: 512 slots of 16B per tensor-tile
    const int s0 = tid, s1 = tid + 256;
    const int r0_ = s0 >> 2, k0_ = (s0 & 3) * 8;
    const int r1_ = s1 >> 2, k1_ = (s1 & 3) * 8;
    (void)ar0;

    for (int k0 = 0; k0 < K; k0 += 32) {
        u16x8 vA0, vA1, vAl0, vAl1, vB0, vB1, vBl0, vBl1;
        if (AMODE == 1) {
            int kk0 = k0 + k0_, kk1 = k0 + k1_;
            size_t g0 = ((size_t)(m0 + r0_) * 16 + (kk0 >> 7)) * 256 + (kk0 & 127);
            size_t g1 = ((size_t)(m0 + r1_) * 16 + (kk1 >> 7)) * 256 + (kk1 & 127);
            vA0  = *reinterpret_cast<const u16x8*>(Ahi + g0);
            vAl0 = *reinterpret_cast<const u16x8*>(Ahi + g0 + 128);
            vA1  = *reinterpret_cast<const u16x8*>(Ahi + g1);
            vAl1 = *reinterpret_cast<const u16x8*>(Ahi + g1 + 128);
        } else {
            size_t g0 = (size_t)(m0 + r0_) * K + k0 + k0_;
            size_t g1 = (size_t)(m0 + r1_) * K + k0 + k1_;
            vA0  = *reinterpret_cast<const u16x8*>(Ahi + g0);
            vAl0 = *reinterpret_cast<const u16x8*>(Alo + g0);
            vA1  = *reinterpret_cast<const u16x8*>(Ahi + g1);
            vAl1 = *reinterpret_cast<const u16x8*>(Alo + g1);
        }
        {
            size_t g0 = (size_t)(n0 + r0_) * K + k0 + k0_;
            size_t g1 = (size_t)(n0 + r1_) * K + k0 + k1_;
            vB0  = *reinterpret_cast<const u16x8*>(BThi + g0);
            vBl0 = *reinterpret_cast<const u16x8*>(BTlo + g0);
            vB1  = *reinterpret_cast<const u16x8*>(BThi + g1);
            vBl1 = *reinterpret_cast<const u16x8*>(BTlo + g1);
        }
        __syncthreads();
        *reinterpret_cast<u16x8*>(&AsH[r0_][k0_]) = vA0;
        *reinterpret_cast<u16x8*>(&AsH[r1_][k1_]) = vA1;
        *reinterpret_cast<u16x8*>(&AsL[r0_][k0_]) = vAl0;
        *reinterpret_cast<u16x8*>(&AsL[r1_][k1_]) = vAl1;
        *reinterpret_cast<u16x8*>(&BsH[r0_][k0_]) = vB0;
        *reinterpret_cast<u16x8*>(&BsH[r1_][k1_]) = vB1;
        *reinterpret_cast<u16x8*>(&BsL[r0_][k0_]) = vBl0;
        *reinterpret_cast<u16x8*>(&BsL[r1_][k1_]) = vBl1;
        __syncthreads();

        const int fr = lane & 15, fk = (lane >> 4) * 8;
        bf16x8 ah[4], al[4];
        #pragma unroll
        for (int mi = 0; mi < 4; ++mi) {
            ah[mi] = *reinterpret_cast<const bf16x8*>(&AsH[wm + mi * 16 + fr][fk]);
            al[mi] = *reinterpret_cast<const bf16x8*>(&AsL[wm + mi * 16 + fr][fk]);
        }
        #pragma unroll
        for (int ni = 0; ni < 4; ++ni) {
            bf16x8 bh = *reinterpret_cast<const bf16x8*>(&BsH[wn + ni * 16 + fr][fk]);
            bf16x8 bl = *reinterpret_cast<const bf16x8*>(&BsL[wn + ni * 16 + fr][fk]);
            #pragma unroll
            for (int mi = 0; mi < 4; ++mi) {
                acc[mi][ni] = __builtin_amdgcn_mfma_f32_16x16x32_bf16(ah[mi], bh, acc[mi][ni], 0, 0, 0);
                acc[mi][ni] = __builtin_amdgcn_mfma_f32_16x16x32_bf16(ah[mi], bl, acc[mi][ni], 0, 0, 0);
                acc[mi][ni] = __builtin_amdgcn_mfma_f32_16x16x32_bf16(al[mi], bh, acc[mi][ni], 0, 0, 0);
            }
        }
    }

    const int fr = lane & 15, fq = lane >> 4;
    #pragma unroll
    for (int ni = 0; ni < 4; ++ni) {
        int col = n0 + wn + ni * 16 + fr;
        float bv = bias[col];
        #pragma unroll
        for (int mi = 0; mi < 4; ++mi) {
            #pragma unroll
            for (int r = 0; r < 4; ++r) {
                int row = m0 + wm + mi * 16 + fq * 4 + r;
                float v = acc[mi][ni][r] + bv;
                if (GELU) v = gelu_exact(v);
                if (OMODE == 0) {
                    Cf[(size_t)row * N + col] = v;
                } else {
                    unsigned short h, l; split_bf16(v, h, l);
                    Ohi[(size_t)row * N + col] = h;
                    Olo[(size_t)row * N + col] = l;
                }
            }
        }
    }
}

__global__ void loss_fin_kernel(const float* __restrict__ acc, float* __restrict__ out) {
    out[0] = acc[0] * (1.0f / 8388608.0f);
}

extern "C" void kernel_launch(void* const* d_in, const int* in_sizes, int n_in,
                              void* d_out, int out_size, void* d_ws, size_t ws_size,
                              hipStream_t stream) {
    const float* x   = (const float*)d_in[0];
    const float* eW1 = (const float*)d_in[1];
    const float* eb1 = (const float*)d_in[2];
    const float* eW2 = (const float*)d_in[3];
    const float* eb2 = (const float*)d_in[4];
    const float* eW3 = (const float*)d_in[5];
    const float* eb3 = (const float*)d_in[6];
    const float* dW1 = (const float*)d_in[7];
    const float* db1 = (const float*)d_in[8];
    const float* dW2 = (const float*)d_in[9];
    const float* db2 = (const float*)d_in[10];
    const float* dW3 = (const float*)d_in[11];
    const float* db3 = (const float*)d_in[12];
    const float* cb  = (const float*)d_in[13];

    float* out = (float*)d_out;
    float* ws  = (float*)d_ws;

    float* h1    = ws + H1_OFF;
    float* h2    = ws + H2_OFF;
    float* z     = ws + Z_OFF;
    float* cbT   = ws + CBT_OFF;
    float* cnorm = ws + CNORM_OFF;
    float* lacc  = ws + LACC_OFF;

    unsigned short* qpack = (unsigned short*)z;
    unsigned short* h1hi = (unsigned short*)h1;
    unsigned short* h1lo = (unsigned short*)(h1 + 1048576);
    unsigned short* h2hi = (unsigned short*)h2;
    unsigned short* h2lo = (unsigned short*)(h2 + 1048576);
    unsigned short* wt   = (unsigned short*)(ws + WT_OFF);
    unsigned short* W1TH = wt;
    unsigned short* W1TL = wt + 1048576u;
    unsigned short* W2TH = wt + 2097152u;
    unsigned short* W2TL = wt + 2359296u;
    unsigned short* W3TH = wt + 2621440u;
    unsigned short* W3TL = wt + 3145728u;

    hipMemsetAsync(lacc, 0, sizeof(float), stream);
    cnorm_kernel<<<NCODE, 128, 0, stream>>>(cb, cnorm);
    transpose_f32_kernel<<<dim3(EMB / 32, NCODE / 32), dim3(32, 8), 0, stream>>>(cb, cbT, NCODE, EMB);
    wsplitT_kernel<<<dim3(HID / 32, LAT / 32),    dim3(32, 8), 0, stream>>>(dW1, W1TH, W1TL, LAT, HID);
    wsplitT_kernel<<<dim3(HID / 32, HID / 32),    dim3(32, 8), 0, stream>>>(dW2, W2TH, W2TL, HID, HID);
    wsplitT_kernel<<<dim3(IN_DIM / 32, HID / 32), dim3(32, 8), 0, stream>>>(dW3, W3TH, W3TL, HID, IN_DIM);

    // encoder (fp32, precision-critical for indices)
    gemm_bias_kernel<true ><<<dim3(BDIM / 64, HID / 64), 256, 0, stream>>>(x,  eW1, eb1, h1, BDIM, HID, IN_DIM);
    gemm_bias_kernel<true ><<<dim3(BDIM / 64, HID / 64), 256, 0, stream>>>(h1, eW2, eb2, h2, BDIM, HID, HID);
    gemm_bias_kernel<false><<<dim3(BDIM / 64, LAT / 64), 256, 0, stream>>>(h2, eW3, eb3, z,  BDIM, LAT, HID);

    // VQ: fp32 argmin + in-place qpack write + loss
    vq2_kernel<<<NROWS / 64, 256, 0, stream>>>(z, qpack, cbT, cb, cnorm, out + OUT_IDX, lacc);

    // decoder (split-bf16 3-product MFMA)
    mfma_gemm_kernel<1, true, 1><<<dim3(BDIM / 128, HID / 128), 256, 0, stream>>>(
        qpack, nullptr, W1TH, W1TL, db1, nullptr, h1hi, h1lo, BDIM, HID, LAT);
    mfma_gemm_kernel<0, true, 1><<<dim3(BDIM / 128, HID / 128), 256, 0, stream>>>(
        h1hi, h1lo, W2TH, W2TL, db2, nullptr, h2hi, h2lo, BDIM, HID, HID);
    mfma_gemm_kernel<0, false, 0><<<dim3(BDIM / 128, IN_DIM / 128), 256, 0, stream>>>(
        h2hi, h2lo, W3TH, W3TL, db3, out, nullptr, nullptr, BDIM, IN_DIM, HID);

    loss_fin_kernel<<<1, 1, 0, stream>>>(lacc, out + OUT_LOSS);
}